// Round 19
// baseline (350.713 us; speedup 1.0000x reference)
//
#include <hip/hip_runtime.h>
#include <hip/hip_bf16.h>

// GRNN tree transform v15: r18 (best, 216us) + tailA/tailB merged into ONE
// launch with an exit-barrier: all 1024 blocks run tailA, atomically count
// arrivals (0xAA-CAS init, r7-proven), blocks >=64 exit; blocks 0..63 spin
// for 1024 then run tailB. Spinners hold <=64 of 512 resident slots -> no
// deadlock. Saves one launch boundary. k_lvl11 keeps r18's hoisted gathers.

#define NF 7
#define NH 128
#define XSTR 136      // k_inner xs stride (bf16)
#define XSTR3 392     // 384 + 8 pad (row 784 B, 16B-aligned)

typedef __bf16 bf16;
typedef __bf16 bf16x8 __attribute__((ext_vector_type(8)));
typedef float floatx16 __attribute__((ext_vector_type(16)));

__device__ __forceinline__ float ftanh(float x){
    float e = __expf(2.0f * x);
    return 1.0f - __fdividef(2.0f, e + 1.0f);
}

// ---------- launch 1: tiny prep ----------
// grid 197: [0,4) ids_A | 4: ids_B + w_ub | [5,197) wcast
__global__ __launch_bounds__(256) void k_prep0(
    const int2* __restrict__ children,
    const float* __restrict__ w_u, const float* __restrict__ b_u,
    const float* __restrict__ w_h,
    int* __restrict__ ids_A, int* __restrict__ ids_B,
    bf16* __restrict__ wb, bf16* __restrict__ w_ub)
{
    const int t = threadIdx.x;
    const int b = blockIdx.x;
    if (b < 4){
        int root = b * 256 + t;               // 0..1023
        int* base = ids_A + root * 128;
        const int2* ch4 = children + 960;
        const int2* ch5 = children + 1984;
        const int2* ch6 = children + 4032;
        const int2* ch7 = children + 8128;
        const int2* ch8 = children + 16320;
        const int2* ch9 = children + 32704;
        int l5[2], l6[4], l7[8], l8[16], l9[32];
        { int2 c = ch4[root]; l5[0] = c.x; l5[1] = c.y; }
        #pragma unroll
        for (int k = 0; k < 2; ++k){ int2 c = ch5[l5[k]]; l6[2*k] = c.x; l6[2*k+1] = c.y; }
        #pragma unroll
        for (int k = 0; k < 4; ++k){ int2 c = ch6[l6[k]]; l7[2*k] = c.x; l7[2*k+1] = c.y; }
        #pragma unroll
        for (int k = 0; k < 8; ++k){ int2 c = ch7[l7[k]]; l8[2*k] = c.x; l8[2*k+1] = c.y; }
        #pragma unroll
        for (int k = 0; k < 16; ++k){ int2 c = ch8[l8[k]]; l9[2*k] = c.x; l9[2*k+1] = c.y; }
        base[0] = root;
        base[1] = l5[0]; base[2] = l5[1];
        #pragma unroll
        for (int k = 0; k < 4; ++k)  base[3 + k]  = l6[k];
        #pragma unroll
        for (int k = 0; k < 8; ++k)  base[7 + k]  = l7[k];
        #pragma unroll
        for (int k = 0; k < 16; ++k) base[15 + k] = l8[k];
        #pragma unroll
        for (int k = 0; k < 32; ++k) base[31 + k] = l9[k];
        #pragma unroll
        for (int k = 0; k < 32; ++k){
            int2 c = ch9[l9[k]];
            base[63 + 2*k] = c.x; base[64 + 2*k] = c.y;
        }
    } else if (b == 4){
        if (t < 64){
            int root = t;
            int* base = ids_B + root * 32;
            const int2* ch0 = children;
            const int2* ch1 = children + 64;
            const int2* ch2 = children + 192;
            const int2* ch3 = children + 448;
            int l1[2], l2[4], l3[8];
            { int2 c = ch0[root]; l1[0] = c.x; l1[1] = c.y; }
            #pragma unroll
            for (int k = 0; k < 2; ++k){ int2 c = ch1[l1[k]]; l2[2*k] = c.x; l2[2*k+1] = c.y; }
            #pragma unroll
            for (int k = 0; k < 4; ++k){ int2 c = ch2[l2[k]]; l3[2*k] = c.x; l3[2*k+1] = c.y; }
            base[0] = root;
            base[1] = l1[0]; base[2] = l1[1];
            #pragma unroll
            for (int k = 0; k < 4; ++k) base[3 + k] = l2[k];
            #pragma unroll
            for (int k = 0; k < 8; ++k) base[7 + k] = l3[k];
            #pragma unroll
            for (int k = 0; k < 8; ++k){
                int2 c = ch3[l3[k]];
                base[15 + 2*k] = c.x; base[16 + 2*k] = c.y;
            }
        } else if (t < 192){
            int col = t - 64;                 // w_ub row: [128][16]
            union { uint4 u4[2]; bf16 h[16]; } row;
            #pragma unroll
            for (int f = 0; f < NF; ++f) row.h[f] = (bf16)w_u[col * NF + f];
            row.h[7] = (bf16)b_u[col];        // pairs with A's 1.0 at k=7
            #pragma unroll
            for (int k = 8; k < 16; ++k) row.h[k] = (bf16)0.0f;
            *(uint4*)&w_ub[col * 16]     = row.u4[0];
            *(uint4*)&w_ub[col * 16 + 8] = row.u4[1];
        }
    } else {
        int idx = (b - 5) * 256 + t;          // < 49152
        wb[idx] = (bf16)w_h[idx];
    }
}

// ---------- launch 2: level 11 main + u_small fused (r18-proven) ----------
__global__ __launch_bounds__(256, 2) void k_lvl11(
    const float* __restrict__ contents, const int2* __restrict__ children,
    const float* __restrict__ w_u, const float* __restrict__ b_u,
    const bf16* __restrict__ w_ub, const bf16* __restrict__ wb,
    const float* __restrict__ b_h, bf16* __restrict__ emb11,
    unsigned int* __restrict__ usm_u32)
{
    __shared__ bf16 xs[64 * XSTR3];   // 50176 B
    __shared__ int chS[128];          // 512 B -> 50688 B total, 3 blocks/CU
    const int t = threadIdx.x;
    const int b = blockIdx.x;

    if (b >= 2048){
        // u_small tile: rows (b-2048)*128 .. +127 (levels 0..9; fp32-exact)
        float* csL = (float*)xs;      // 4 KB alias
        const size_t srow = (size_t)(b - 2048) * 128;
        if (t < 224){
            float4 v = ((const float4*)(contents + srow * NF))[t];
            int e = t * 4;
            float vv[4] = {v.x, v.y, v.z, v.w};
            #pragma unroll
            for (int r = 0; r < 4; ++r){ int ee = e + r; csL[(ee/7)*8 + (ee%7)] = vv[r]; }
        }
        const int cp = t & 63;
        const int quarter = t >> 6;
        float wu0[NF], wu1[NF];
        const float* w0 = w_u + (size_t)(2 * cp) * NF;
        #pragma unroll
        for (int f = 0; f < NF; ++f){ wu0[f] = w0[f]; wu1[f] = w0[NF + f]; }
        const float bu0 = b_u[2 * cp], bu1 = b_u[2 * cp + 1];
        __syncthreads();
        #pragma unroll 4
        for (int i = 0; i < 32; ++i){
            int node = quarter * 32 + i;
            float4 c0 = *(const float4*)&csL[node * 8];
            float4 c1 = *(const float4*)&csL[node * 8 + 4];
            float a0 = bu0, a1 = bu1;
            a0 = fmaf(c0.x, wu0[0], a0); a1 = fmaf(c0.x, wu1[0], a1);
            a0 = fmaf(c0.y, wu0[1], a0); a1 = fmaf(c0.y, wu1[1], a1);
            a0 = fmaf(c0.z, wu0[2], a0); a1 = fmaf(c0.z, wu1[2], a1);
            a0 = fmaf(c0.w, wu0[3], a0); a1 = fmaf(c0.w, wu1[3], a1);
            a0 = fmaf(c1.x, wu0[4], a0); a1 = fmaf(c1.x, wu1[4], a1);
            a0 = fmaf(c1.y, wu0[5], a0); a1 = fmaf(c1.y, wu1[5], a1);
            a0 = fmaf(c1.z, wu0[6], a0); a1 = fmaf(c1.z, wu1[6], a1);
            union { unsigned int u; bf16 h[2]; } pk;
            pk.h[0] = (bf16)ftanh(a0);
            pk.h[1] = (bf16)ftanh(a1);
            usm_u32[(srow + node) * 64 + cp] = pk.u;
        }
        return;
    }

    // ---- main path: 64 level-11 nodes ----
    const int node0 = b * 64;
    const int2* ch11 = children + 131008;
    const float* cont11 = contents + (size_t)131008 * NF;
    const float* contL  = contents + (size_t)262080 * NF;

    if (t < 64){ int2 c = ch11[node0 + t]; chS[2*t] = c.x; chS[2*t + 1] = c.y; }

    const int lane = t & 63;
    const int ct = t >> 6;
    const int m = lane & 31;
    const int q = lane >> 5;
    const int colg = ct * 32 + m;
    const bf16x8 bu = *(const bf16x8*)(w_ub + (size_t)colg * 16 + q * 8);
    __syncthreads();   // chS ready

    // hoisted: all 6 tiles' contents gathers up-front (q=0 lanes)
    float rows[6][NF];
    if (q == 0){
        #pragma unroll
        for (int tile = 0; tile < 6; ++tile){
            const float* src;
            if (tile < 4) src = contL + (size_t)chS[tile * 32 + m] * NF;
            else          src = cont11 + (size_t)(node0 + (tile - 4) * 32 + m) * NF;
            #pragma unroll
            for (int f = 0; f < NF; ++f) rows[tile][f] = src[f];
        }
    }

    #pragma unroll
    for (int tile = 0; tile < 6; ++tile){
        bf16x8 a = {bf16(0.f),bf16(0.f),bf16(0.f),bf16(0.f),
                    bf16(0.f),bf16(0.f),bf16(0.f),bf16(0.f)};
        if (q == 0){
            union { bf16x8 v; bf16 h[8]; } u8;
            #pragma unroll
            for (int f = 0; f < NF; ++f) u8.h[f] = (bf16)rows[tile][f];
            u8.h[7] = (bf16)1.0f;
            a = u8.v;
        }
        floatx16 acc = {0,0,0,0,0,0,0,0,0,0,0,0,0,0,0,0};
        acc = __builtin_amdgcn_mfma_f32_32x32x16_bf16(a, bu, acc, 0, 0, 0);
        #pragma unroll
        for (int r = 0; r < 16; ++r){
            int row = (r & 3) + 8 * (r >> 2) + 4 * q;
            bf16 hv = (bf16)ftanh(acc[r]);
            if (tile < 4){
                int c = tile * 32 + row;
                xs[(c >> 1) * XSTR3 + (c & 1) * 128 + colg] = hv;
            } else {
                int i = (tile - 4) * 32 + row;
                xs[i * XSTR3 + 256 + colg] = hv;
            }
        }
    }
    __syncthreads();   // xs fully staged

    floatx16 acc0 = {0,0,0,0,0,0,0,0,0,0,0,0,0,0,0,0};
    floatx16 acc1 = {0,0,0,0,0,0,0,0,0,0,0,0,0,0,0,0};
    const bf16* bq = wb + (size_t)colg * 384 + q * 8;
    const bf16* xa = &xs[m * XSTR3 + q * 8];
    #pragma unroll
    for (int grp = 0; grp < 3; ++grp){
        bf16x8 bfr[8];
        #pragma unroll
        for (int kk = 0; kk < 8; ++kk)
            bfr[kk] = *(const bf16x8*)(bq + grp * 128 + kk * 16);
        #pragma unroll
        for (int kk = 0; kk < 8; ++kk){
            bf16x8 a0 = *(const bf16x8*)(xa + grp * 128 + kk * 16);
            bf16x8 a1 = *(const bf16x8*)(xa + grp * 128 + kk * 16 + 32 * XSTR3);
            acc0 = __builtin_amdgcn_mfma_f32_32x32x16_bf16(a0, bfr[kk], acc0, 0, 0, 0);
            acc1 = __builtin_amdgcn_mfma_f32_32x32x16_bf16(a1, bfr[kk], acc1, 0, 0, 0);
        }
    }

    const float bv = b_h[colg];
    #pragma unroll
    for (int nt = 0; nt < 2; ++nt){
        const floatx16* accp = nt ? &acc1 : &acc0;
        #pragma unroll
        for (int r = 0; r < 16; ++r){
            int row  = (r & 3) + 8 * (r >> 2) + 4 * q;
            int node = node0 + nt * 32 + row;
            emb11[(size_t)node * NH + colg] = (bf16)ftanh((*accp)[r] + bv);
        }
    }
}

// ---------- launch 3: k_inner j=10 (r10-proven, unchanged) ----------
__global__ __launch_bounds__(256, 4) void k_inner(
    const int2* __restrict__ children, const float* __restrict__ contents,
    const float* __restrict__ w_u, const float* __restrict__ b_u,
    const bf16* __restrict__ wb, const float* __restrict__ b_h,
    const bf16* __restrict__ emb_next, bf16* __restrict__ out_b)
{
    __shared__ bf16 xs[64 * XSTR];
    __shared__ int2 ch_s[64];
    __shared__ float cs[64 * 8];
    const int t = threadIdx.x;
    const int block0 = blockIdx.x * 64;
    if (t < 64) ch_s[t] = children[block0 + t];
    if (t < 112){
        float4 v = ((const float4*)(contents + (size_t)block0 * NF))[t];
        int e = t * 4;
        float vv[4] = {v.x, v.y, v.z, v.w};
        #pragma unroll
        for (int r = 0; r < 4; ++r){ int ee = e + r; cs[(ee/7)*8 + (ee%7)] = vv[r]; }
    }
    const int cp = t & 63;
    const int quarter = t >> 6;
    float wu0[NF], wu1[NF];
    {
        const float* w0 = w_u + (size_t)(2 * cp) * NF;
        #pragma unroll
        for (int f = 0; f < NF; ++f){ wu0[f] = w0[f]; wu1[f] = w0[NF + f]; }
    }
    const float bu0 = b_u[2 * cp], bu1 = b_u[2 * cp + 1];
    const int lane = t & 63;
    const int ct = t >> 6;
    const int m = lane & 31;
    const int q = lane >> 5;
    floatx16 acc0 = {0,0,0,0,0,0,0,0,0,0,0,0,0,0,0,0};
    floatx16 acc1 = {0,0,0,0,0,0,0,0,0,0,0,0,0,0,0,0};
    const bf16* bq = wb + ((size_t)(ct * 32 + m) * 384 + q * 8);
    #pragma unroll 1
    for (int p = 0; p < 3; ++p){
        __syncthreads();
        if (p < 2){
            #pragma unroll
            for (int r = 0; r < 4; ++r){
                int task = r * 256 + t;
                int i = task >> 4, part = task & 15;
                int row = (p == 0) ? ch_s[i].x : ch_s[i].y;
                uint4 v = *(const uint4*)(emb_next + (size_t)row * NH + part * 8);
                *(uint4*)&xs[i * XSTR + part * 8] = v;
            }
        } else {
            #pragma unroll 4
            for (int i = 0; i < 16; ++i){
                int node = quarter * 16 + i;
                float4 c0 = *(const float4*)&cs[node * 8];
                float4 c1 = *(const float4*)&cs[node * 8 + 4];
                float a0 = bu0, a1 = bu1;
                a0 = fmaf(c0.x, wu0[0], a0); a1 = fmaf(c0.x, wu1[0], a1);
                a0 = fmaf(c0.y, wu0[1], a0); a1 = fmaf(c0.y, wu1[1], a1);
                a0 = fmaf(c0.z, wu0[2], a0); a1 = fmaf(c0.z, wu1[2], a1);
                a0 = fmaf(c0.w, wu0[3], a0); a1 = fmaf(c0.w, wu1[3], a1);
                a0 = fmaf(c1.x, wu0[4], a0); a1 = fmaf(c1.x, wu1[4], a1);
                a0 = fmaf(c1.y, wu0[5], a0); a1 = fmaf(c1.y, wu1[5], a1);
                a0 = fmaf(c1.z, wu0[6], a0); a1 = fmaf(c1.z, wu1[6], a1);
                union { unsigned int u; bf16 h[2]; } pk;
                pk.h[0] = (bf16)ftanh(a0);
                pk.h[1] = (bf16)ftanh(a1);
                ((unsigned int*)xs)[node * (XSTR / 2) + cp] = pk.u;
            }
        }
        bf16x8 bfr[8];
        #pragma unroll
        for (int kk = 0; kk < 8; ++kk)
            bfr[kk] = *(const bf16x8*)(bq + p * 128 + kk * 16);
        __syncthreads();
        const bf16* xa = &xs[m * XSTR + q * 8];
        #pragma unroll
        for (int kk = 0; kk < 8; ++kk){
            bf16x8 a0 = *(const bf16x8*)(xa + kk * 16);
            bf16x8 a1 = *(const bf16x8*)(xa + kk * 16 + 32 * XSTR);
            acc0 = __builtin_amdgcn_mfma_f32_32x32x16_bf16(a0, bfr[kk], acc0, 0, 0, 0);
            acc1 = __builtin_amdgcn_mfma_f32_32x32x16_bf16(a1, bfr[kk], acc1, 0, 0, 0);
        }
    }
    const int colg = ct * 32 + m;
    const float bv = b_h[colg];
    #pragma unroll
    for (int nt = 0; nt < 2; ++nt){
        const floatx16* accp = nt ? &acc1 : &acc0;
        #pragma unroll
        for (int r = 0; r < 16; ++r){
            int row  = (r & 3) + 8 * (r >> 2) + 4 * q;
            int node = block0 + nt * 32 + row;
            out_b[(size_t)node * NH + colg] = (bf16)ftanh((*accp)[r] + bv);
        }
    }
}

// ---------- launch 4: tailA + exit-barrier + tailB (merged) ----------
__global__ __launch_bounds__(256, 2) void k_tailAB(
    const int* __restrict__ ids_A, const int* __restrict__ ids_B,
    const bf16* __restrict__ u_small, const bf16* __restrict__ wb,
    const float* __restrict__ b_h, const bf16* __restrict__ emb10,
    bf16* __restrict__ emb4, float* __restrict__ out_f,
    unsigned int* __restrict__ bar)
{
    __shared__ bf16 xs[32 * XSTR3];    // 25088 B (tailB reuses prefix)
    __shared__ bf16 embL[32 * 136];    // 8704 B
    __shared__ int ids[128];           // 512 B -> 34304 B
    const int t = threadIdx.x, root = blockIdx.x;
    const int ct = t >> 6, lane = t & 63, m = lane & 31, q = lane >> 5;
    const float bv = b_h[ct * 32 + m];
    const bf16* bq = wb + ((size_t)(ct * 32 + m) * 384 + q * 8);

    // ---- phase A: levels 9..4 (r10-proven tailA body) ----
    if (t < 32) ((uint4*)ids)[t] = ((const uint4*)(ids_A + root * 128))[t];
    __syncthreads();
    #pragma unroll 1
    for (int l = 9; l >= 4; --l){
        const int n = 1 << (l - 4);
        #pragma unroll 1
        for (int r = 0; r < 4; ++r){
            int task = r * 256 + t;
            if (task < n * 32){
                int i = task >> 5, half = (task >> 4) & 1, part = task & 15;
                uint4 v;
                if (l == 9) v = *(const uint4*)(emb10 + (size_t)ids[63 + 2*i + half] * NH + part * 8);
                else        v = *(uint4*)&embL[(2*i + half) * 136 + part * 8];
                *(uint4*)&xs[i * XSTR3 + half * 128 + part * 8] = v;
            }
        }
        #pragma unroll 1
        for (int r = 0; r < 2; ++r){
            int task = r * 256 + t;
            if (task < n * 16){
                int i = task >> 4, part = task & 15;
                size_t row = (size_t)64 * ((1u << l) - 1) + ids[(n - 1) + i];
                *(uint4*)&xs[i * XSTR3 + 256 + part * 8] =
                    *(const uint4*)(u_small + row * NH + part * 8);
            }
        }
        __syncthreads();
        floatx16 accs[3];
        #pragma unroll
        for (int g = 0; g < 3; ++g) accs[g] = (floatx16){0,0,0,0,0,0,0,0,0,0,0,0,0,0,0,0};
        const bf16* xa = &xs[m * XSTR3 + q * 8];
        #pragma unroll
        for (int grp = 0; grp < 3; ++grp){
            bf16x8 bfr[8];
            #pragma unroll
            for (int kk = 0; kk < 8; ++kk)
                bfr[kk] = *(const bf16x8*)(bq + grp * 128 + kk * 16);
            #pragma unroll
            for (int kk = 0; kk < 8; ++kk){
                bf16x8 a0 = *(const bf16x8*)(xa + grp * 128 + kk * 16);
                accs[grp] = __builtin_amdgcn_mfma_f32_32x32x16_bf16(a0, bfr[kk], accs[grp], 0, 0, 0);
            }
        }
        floatx16 acc = accs[0] + accs[1] + accs[2];
        __syncthreads();
        #pragma unroll
        for (int r = 0; r < 16; ++r){
            int row = (r & 3) + 8 * (r >> 2) + 4 * q;
            if (row < n){
                float v = ftanh(acc[r] + bv);
                if (l > 4) embL[row * 136 + ct * 32 + m] = (bf16)v;
                else       emb4[(size_t)root * NH + ct * 32 + m] = (bf16)v;
            }
        }
        __syncthreads();
    }

    // ---- exit-barrier: count arrivals; only blocks 0..63 wait ----
    __threadfence();
    __syncthreads();
    if (t == 0){
        unsigned int expected = 0xAAAAAAAAu;
        __hip_atomic_compare_exchange_strong(bar, &expected, 0u,
            __ATOMIC_ACQ_REL, __ATOMIC_RELAXED, __HIP_MEMORY_SCOPE_AGENT);
        __hip_atomic_fetch_add(bar, 1u, __ATOMIC_ACQ_REL, __HIP_MEMORY_SCOPE_AGENT);
    }
    if (root >= 64) return;
    if (t == 0){
        while (__hip_atomic_load(bar, __ATOMIC_ACQUIRE, __HIP_MEMORY_SCOPE_AGENT) < 1024u)
            __builtin_amdgcn_s_sleep(8);
    }
    __syncthreads();

    // ---- phase B: levels 3..0 (r10-proven tailB body; reuses xs/embL/ids) ----
    if (t < 8) ((uint4*)ids)[t] = ((const uint4*)(ids_B + root * 32))[t];
    __syncthreads();
    #pragma unroll 1
    for (int l = 3; l >= 0; --l){
        const int n = 1 << l;
        {
            int task = t;
            if (task < n * 32){
                int i = task >> 5, half = (task >> 4) & 1, part = task & 15;
                uint4 v;
                if (l == 3) v = *(const uint4*)(emb4 + (size_t)ids[15 + 2*i + half] * NH + part * 8);
                else        v = *(uint4*)&embL[(2*i + half) * 136 + part * 8];
                *(uint4*)&xs[i * XSTR3 + half * 128 + part * 8] = v;
            }
            if (task < n * 16){
                int i = task >> 4, part = task & 15;
                size_t row = (size_t)64 * ((1u << l) - 1) + ids[(n - 1) + i];
                *(uint4*)&xs[i * XSTR3 + 256 + part * 8] =
                    *(const uint4*)(u_small + row * NH + part * 8);
            }
        }
        __syncthreads();
        floatx16 accs[3];
        #pragma unroll
        for (int g = 0; g < 3; ++g) accs[g] = (floatx16){0,0,0,0,0,0,0,0,0,0,0,0,0,0,0,0};
        const bf16* xa = &xs[m * XSTR3 + q * 8];
        #pragma unroll
        for (int grp = 0; grp < 3; ++grp){
            bf16x8 bfr[8];
            #pragma unroll
            for (int kk = 0; kk < 8; ++kk)
                bfr[kk] = *(const bf16x8*)(bq + grp * 128 + kk * 16);
            #pragma unroll
            for (int kk = 0; kk < 8; ++kk){
                bf16x8 a0 = *(const bf16x8*)(xa + grp * 128 + kk * 16);
                accs[grp] = __builtin_amdgcn_mfma_f32_32x32x16_bf16(a0, bfr[kk], accs[grp], 0, 0, 0);
            }
        }
        floatx16 acc = accs[0] + accs[1] + accs[2];
        __syncthreads();
        #pragma unroll
        for (int r = 0; r < 16; ++r){
            int row = (r & 3) + 8 * (r >> 2) + 4 * q;
            if (row < n){
                float v = ftanh(acc[r] + bv);
                if (l > 0) embL[row * 136 + ct * 32 + m] = (bf16)v;
                else       out_f[(size_t)root * NH + ct * 32 + m] = v;
            }
        }
        __syncthreads();
    }
}

// ---------- launcher ----------
extern "C" void kernel_launch(void* const* d_in, const int* in_sizes, int n_in,
                              void* d_out, int out_size, void* d_ws, size_t ws_size,
                              hipStream_t stream){
    const float* contents = (const float*)d_in[0];
    const int2*  children = (const int2*)d_in[1];
    const float* w_u      = (const float*)d_in[2];
    const float* b_u      = (const float*)d_in[3];
    const float* w_h      = (const float*)d_in[4];
    const float* b_h      = (const float*)d_in[5];
    float* outf = (float*)d_out;

    // ws: embA 16.8MB (emb10) | embB 33.6MB (emb11/emb4) | wb 96KB |
    //     u_small 16.8MB | ids_A 512KB | ids_B 8KB | w_ub 4KB | bar
    bf16* embA    = (bf16*)d_ws;
    bf16* embB    = embA + (size_t)65536 * NH;
    bf16* wb      = embB + (size_t)131072 * NH;
    bf16* u_small = wb + (size_t)NH * 384;
    int*  ids_A   = (int*)(u_small + (size_t)65536 * NH);
    int*  ids_B   = ids_A + 1024 * 128;
    bf16* w_ub    = (bf16*)(ids_B + 64 * 32);
    unsigned int* bar = (unsigned int*)(w_ub + 128 * 16);

    hipLaunchKernelGGL(k_prep0, dim3(197), dim3(256), 0, stream,
                       children, w_u, b_u, w_h, ids_A, ids_B, wb, w_ub);
    hipLaunchKernelGGL(k_lvl11, dim3(2560), dim3(256), 0, stream,
                       contents, children, w_u, b_u, w_ub, wb, b_h,
                       embB, (unsigned int*)u_small);
    hipLaunchKernelGGL(k_inner, dim3(1024), dim3(256), 0, stream,
                       children + 65472, contents + (size_t)65472 * NF,
                       w_u, b_u, wb, b_h, embB, embA);
    hipLaunchKernelGGL(k_tailAB, dim3(1024), dim3(256), 0, stream,
                       ids_A, ids_B, u_small, wb, b_h, embA, embB, outf, bar);
}

// Round 20
// 215.394 us; speedup vs baseline: 1.6282x; 1.6282x over previous
//
#include <hip/hip_runtime.h>
#include <hip/hip_bf16.h>

// GRNN tree transform v14 (REVERT to round-18 best, 216.5us).
// r19's tailA/tailB exit-barrier merge regressed to 350us (third confirmation
// that cross-workgroup waits cost >=100us on MI355X: r6 coop sync, r14 merged
// barrier, r19 exit-barrier). Launch boundaries are the cheapest sync.
//  1. k_prep0: wb cast + w_ub + ids_A + ids_B
//  2. k_lvl11: level-11 main (emb12 fused away; u via MFMA; hoisted gathers)
//              + u_small tiles fused as extra blocks
//  3. k_inner j=10   4. k_tailA (levels 9..4)   5. k_tailB (levels 3..0)

#define NF 7
#define NH 128
#define XSTR 136      // k_inner xs stride (bf16)
#define XSTR3 392     // 384 + 8 pad (row 784 B, 16B-aligned)

typedef __bf16 bf16;
typedef __bf16 bf16x8 __attribute__((ext_vector_type(8)));
typedef float floatx16 __attribute__((ext_vector_type(16)));

__device__ __forceinline__ float ftanh(float x){
    float e = __expf(2.0f * x);
    return 1.0f - __fdividef(2.0f, e + 1.0f);
}

// ---------- launch 1: tiny prep ----------
// grid 197: [0,4) ids_A | 4: ids_B + w_ub | [5,197) wcast
__global__ __launch_bounds__(256) void k_prep0(
    const int2* __restrict__ children,
    const float* __restrict__ w_u, const float* __restrict__ b_u,
    const float* __restrict__ w_h,
    int* __restrict__ ids_A, int* __restrict__ ids_B,
    bf16* __restrict__ wb, bf16* __restrict__ w_ub)
{
    const int t = threadIdx.x;
    const int b = blockIdx.x;
    if (b < 4){
        int root = b * 256 + t;               // 0..1023
        int* base = ids_A + root * 128;
        const int2* ch4 = children + 960;
        const int2* ch5 = children + 1984;
        const int2* ch6 = children + 4032;
        const int2* ch7 = children + 8128;
        const int2* ch8 = children + 16320;
        const int2* ch9 = children + 32704;
        int l5[2], l6[4], l7[8], l8[16], l9[32];
        { int2 c = ch4[root]; l5[0] = c.x; l5[1] = c.y; }
        #pragma unroll
        for (int k = 0; k < 2; ++k){ int2 c = ch5[l5[k]]; l6[2*k] = c.x; l6[2*k+1] = c.y; }
        #pragma unroll
        for (int k = 0; k < 4; ++k){ int2 c = ch6[l6[k]]; l7[2*k] = c.x; l7[2*k+1] = c.y; }
        #pragma unroll
        for (int k = 0; k < 8; ++k){ int2 c = ch7[l7[k]]; l8[2*k] = c.x; l8[2*k+1] = c.y; }
        #pragma unroll
        for (int k = 0; k < 16; ++k){ int2 c = ch8[l8[k]]; l9[2*k] = c.x; l9[2*k+1] = c.y; }
        base[0] = root;
        base[1] = l5[0]; base[2] = l5[1];
        #pragma unroll
        for (int k = 0; k < 4; ++k)  base[3 + k]  = l6[k];
        #pragma unroll
        for (int k = 0; k < 8; ++k)  base[7 + k]  = l7[k];
        #pragma unroll
        for (int k = 0; k < 16; ++k) base[15 + k] = l8[k];
        #pragma unroll
        for (int k = 0; k < 32; ++k) base[31 + k] = l9[k];
        #pragma unroll
        for (int k = 0; k < 32; ++k){
            int2 c = ch9[l9[k]];
            base[63 + 2*k] = c.x; base[64 + 2*k] = c.y;
        }
    } else if (b == 4){
        if (t < 64){
            int root = t;
            int* base = ids_B + root * 32;
            const int2* ch0 = children;
            const int2* ch1 = children + 64;
            const int2* ch2 = children + 192;
            const int2* ch3 = children + 448;
            int l1[2], l2[4], l3[8];
            { int2 c = ch0[root]; l1[0] = c.x; l1[1] = c.y; }
            #pragma unroll
            for (int k = 0; k < 2; ++k){ int2 c = ch1[l1[k]]; l2[2*k] = c.x; l2[2*k+1] = c.y; }
            #pragma unroll
            for (int k = 0; k < 4; ++k){ int2 c = ch2[l2[k]]; l3[2*k] = c.x; l3[2*k+1] = c.y; }
            base[0] = root;
            base[1] = l1[0]; base[2] = l1[1];
            #pragma unroll
            for (int k = 0; k < 4; ++k) base[3 + k] = l2[k];
            #pragma unroll
            for (int k = 0; k < 8; ++k) base[7 + k] = l3[k];
            #pragma unroll
            for (int k = 0; k < 8; ++k){
                int2 c = ch3[l3[k]];
                base[15 + 2*k] = c.x; base[16 + 2*k] = c.y;
            }
        } else if (t < 192){
            int col = t - 64;                 // w_ub row: [128][16]
            union { uint4 u4[2]; bf16 h[16]; } row;
            #pragma unroll
            for (int f = 0; f < NF; ++f) row.h[f] = (bf16)w_u[col * NF + f];
            row.h[7] = (bf16)b_u[col];        // pairs with A's 1.0 at k=7
            #pragma unroll
            for (int k = 8; k < 16; ++k) row.h[k] = (bf16)0.0f;
            *(uint4*)&w_ub[col * 16]     = row.u4[0];
            *(uint4*)&w_ub[col * 16 + 8] = row.u4[1];
        }
    } else {
        int idx = (b - 5) * 256 + t;          // < 49152
        wb[idx] = (bf16)w_h[idx];
    }
}

// ---------- launch 2: level 11 main + u_small fused ----------
__global__ __launch_bounds__(256, 2) void k_lvl11(
    const float* __restrict__ contents, const int2* __restrict__ children,
    const float* __restrict__ w_u, const float* __restrict__ b_u,
    const bf16* __restrict__ w_ub, const bf16* __restrict__ wb,
    const float* __restrict__ b_h, bf16* __restrict__ emb11,
    unsigned int* __restrict__ usm_u32)
{
    __shared__ bf16 xs[64 * XSTR3];   // 50176 B
    __shared__ int chS[128];          // 512 B -> 50688 B total, 3 blocks/CU
    const int t = threadIdx.x;
    const int b = blockIdx.x;

    if (b >= 2048){
        // u_small tile: rows (b-2048)*128 .. +127 (levels 0..9; fp32-exact)
        float* csL = (float*)xs;      // 4 KB alias
        const size_t srow = (size_t)(b - 2048) * 128;
        if (t < 224){
            float4 v = ((const float4*)(contents + srow * NF))[t];
            int e = t * 4;
            float vv[4] = {v.x, v.y, v.z, v.w};
            #pragma unroll
            for (int r = 0; r < 4; ++r){ int ee = e + r; csL[(ee/7)*8 + (ee%7)] = vv[r]; }
        }
        const int cp = t & 63;
        const int quarter = t >> 6;
        float wu0[NF], wu1[NF];
        const float* w0 = w_u + (size_t)(2 * cp) * NF;
        #pragma unroll
        for (int f = 0; f < NF; ++f){ wu0[f] = w0[f]; wu1[f] = w0[NF + f]; }
        const float bu0 = b_u[2 * cp], bu1 = b_u[2 * cp + 1];
        __syncthreads();
        #pragma unroll 4
        for (int i = 0; i < 32; ++i){
            int node = quarter * 32 + i;
            float4 c0 = *(const float4*)&csL[node * 8];
            float4 c1 = *(const float4*)&csL[node * 8 + 4];
            float a0 = bu0, a1 = bu1;
            a0 = fmaf(c0.x, wu0[0], a0); a1 = fmaf(c0.x, wu1[0], a1);
            a0 = fmaf(c0.y, wu0[1], a0); a1 = fmaf(c0.y, wu1[1], a1);
            a0 = fmaf(c0.z, wu0[2], a0); a1 = fmaf(c0.z, wu1[2], a1);
            a0 = fmaf(c0.w, wu0[3], a0); a1 = fmaf(c0.w, wu1[3], a1);
            a0 = fmaf(c1.x, wu0[4], a0); a1 = fmaf(c1.x, wu1[4], a1);
            a0 = fmaf(c1.y, wu0[5], a0); a1 = fmaf(c1.y, wu1[5], a1);
            a0 = fmaf(c1.z, wu0[6], a0); a1 = fmaf(c1.z, wu1[6], a1);
            union { unsigned int u; bf16 h[2]; } pk;
            pk.h[0] = (bf16)ftanh(a0);
            pk.h[1] = (bf16)ftanh(a1);
            usm_u32[(srow + node) * 64 + cp] = pk.u;
        }
        return;
    }

    // ---- main path: 64 level-11 nodes ----
    const int node0 = b * 64;
    const int2* ch11 = children + 131008;
    const float* cont11 = contents + (size_t)131008 * NF;
    const float* contL  = contents + (size_t)262080 * NF;

    if (t < 64){ int2 c = ch11[node0 + t]; chS[2*t] = c.x; chS[2*t + 1] = c.y; }

    const int lane = t & 63;
    const int ct = t >> 6;
    const int m = lane & 31;
    const int q = lane >> 5;
    const int colg = ct * 32 + m;
    const bf16x8 bu = *(const bf16x8*)(w_ub + (size_t)colg * 16 + q * 8);
    __syncthreads();   // chS ready

    // hoisted: all 6 tiles' contents gathers up-front (q=0 lanes) -> single
    // HBM latency exposure, fully pipelined.
    float rows[6][NF];
    if (q == 0){
        #pragma unroll
        for (int tile = 0; tile < 6; ++tile){
            const float* src;
            if (tile < 4) src = contL + (size_t)chS[tile * 32 + m] * NF;
            else          src = cont11 + (size_t)(node0 + (tile - 4) * 32 + m) * NF;
            #pragma unroll
            for (int f = 0; f < NF; ++f) rows[tile][f] = src[f];
        }
    }

    // u via MFMA from registers. tiles 0..3 leaf children, 4..5 own nodes.
    #pragma unroll
    for (int tile = 0; tile < 6; ++tile){
        bf16x8 a = {bf16(0.f),bf16(0.f),bf16(0.f),bf16(0.f),
                    bf16(0.f),bf16(0.f),bf16(0.f),bf16(0.f)};
        if (q == 0){
            union { bf16x8 v; bf16 h[8]; } u8;
            #pragma unroll
            for (int f = 0; f < NF; ++f) u8.h[f] = (bf16)rows[tile][f];
            u8.h[7] = (bf16)1.0f;
            a = u8.v;
        }
        floatx16 acc = {0,0,0,0,0,0,0,0,0,0,0,0,0,0,0,0};
        acc = __builtin_amdgcn_mfma_f32_32x32x16_bf16(a, bu, acc, 0, 0, 0);
        #pragma unroll
        for (int r = 0; r < 16; ++r){
            int row = (r & 3) + 8 * (r >> 2) + 4 * q;
            bf16 hv = (bf16)ftanh(acc[r]);
            if (tile < 4){
                int c = tile * 32 + row;
                xs[(c >> 1) * XSTR3 + (c & 1) * 128 + colg] = hv;
            } else {
                int i = (tile - 4) * 32 + row;
                xs[i * XSTR3 + 256 + colg] = hv;
            }
        }
    }
    __syncthreads();   // xs fully staged

    floatx16 acc0 = {0,0,0,0,0,0,0,0,0,0,0,0,0,0,0,0};
    floatx16 acc1 = {0,0,0,0,0,0,0,0,0,0,0,0,0,0,0,0};
    const bf16* bq = wb + (size_t)colg * 384 + q * 8;
    const bf16* xa = &xs[m * XSTR3 + q * 8];
    #pragma unroll
    for (int grp = 0; grp < 3; ++grp){
        bf16x8 bfr[8];
        #pragma unroll
        for (int kk = 0; kk < 8; ++kk)
            bfr[kk] = *(const bf16x8*)(bq + grp * 128 + kk * 16);
        #pragma unroll
        for (int kk = 0; kk < 8; ++kk){
            bf16x8 a0 = *(const bf16x8*)(xa + grp * 128 + kk * 16);
            bf16x8 a1 = *(const bf16x8*)(xa + grp * 128 + kk * 16 + 32 * XSTR3);
            acc0 = __builtin_amdgcn_mfma_f32_32x32x16_bf16(a0, bfr[kk], acc0, 0, 0, 0);
            acc1 = __builtin_amdgcn_mfma_f32_32x32x16_bf16(a1, bfr[kk], acc1, 0, 0, 0);
        }
    }

    const float bv = b_h[colg];
    #pragma unroll
    for (int nt = 0; nt < 2; ++nt){
        const floatx16* accp = nt ? &acc1 : &acc0;
        #pragma unroll
        for (int r = 0; r < 16; ++r){
            int row  = (r & 3) + 8 * (r >> 2) + 4 * q;
            int node = node0 + nt * 32 + row;
            emb11[(size_t)node * NH + colg] = (bf16)ftanh((*accp)[r] + bv);
        }
    }
}

// ---------- launch 3: k_inner j=10 (r10-proven, unchanged) ----------
__global__ __launch_bounds__(256, 4) void k_inner(
    const int2* __restrict__ children, const float* __restrict__ contents,
    const float* __restrict__ w_u, const float* __restrict__ b_u,
    const bf16* __restrict__ wb, const float* __restrict__ b_h,
    const bf16* __restrict__ emb_next, bf16* __restrict__ out_b)
{
    __shared__ bf16 xs[64 * XSTR];
    __shared__ int2 ch_s[64];
    __shared__ float cs[64 * 8];
    const int t = threadIdx.x;
    const int block0 = blockIdx.x * 64;
    if (t < 64) ch_s[t] = children[block0 + t];
    if (t < 112){
        float4 v = ((const float4*)(contents + (size_t)block0 * NF))[t];
        int e = t * 4;
        float vv[4] = {v.x, v.y, v.z, v.w};
        #pragma unroll
        for (int r = 0; r < 4; ++r){ int ee = e + r; cs[(ee/7)*8 + (ee%7)] = vv[r]; }
    }
    const int cp = t & 63;
    const int quarter = t >> 6;
    float wu0[NF], wu1[NF];
    {
        const float* w0 = w_u + (size_t)(2 * cp) * NF;
        #pragma unroll
        for (int f = 0; f < NF; ++f){ wu0[f] = w0[f]; wu1[f] = w0[NF + f]; }
    }
    const float bu0 = b_u[2 * cp], bu1 = b_u[2 * cp + 1];
    const int lane = t & 63;
    const int ct = t >> 6;
    const int m = lane & 31;
    const int q = lane >> 5;
    floatx16 acc0 = {0,0,0,0,0,0,0,0,0,0,0,0,0,0,0,0};
    floatx16 acc1 = {0,0,0,0,0,0,0,0,0,0,0,0,0,0,0,0};
    const bf16* bq = wb + ((size_t)(ct * 32 + m) * 384 + q * 8);
    #pragma unroll 1
    for (int p = 0; p < 3; ++p){
        __syncthreads();
        if (p < 2){
            #pragma unroll
            for (int r = 0; r < 4; ++r){
                int task = r * 256 + t;
                int i = task >> 4, part = task & 15;
                int row = (p == 0) ? ch_s[i].x : ch_s[i].y;
                uint4 v = *(const uint4*)(emb_next + (size_t)row * NH + part * 8);
                *(uint4*)&xs[i * XSTR + part * 8] = v;
            }
        } else {
            #pragma unroll 4
            for (int i = 0; i < 16; ++i){
                int node = quarter * 16 + i;
                float4 c0 = *(const float4*)&cs[node * 8];
                float4 c1 = *(const float4*)&cs[node * 8 + 4];
                float a0 = bu0, a1 = bu1;
                a0 = fmaf(c0.x, wu0[0], a0); a1 = fmaf(c0.x, wu1[0], a1);
                a0 = fmaf(c0.y, wu0[1], a0); a1 = fmaf(c0.y, wu1[1], a1);
                a0 = fmaf(c0.z, wu0[2], a0); a1 = fmaf(c0.z, wu1[2], a1);
                a0 = fmaf(c0.w, wu0[3], a0); a1 = fmaf(c0.w, wu1[3], a1);
                a0 = fmaf(c1.x, wu0[4], a0); a1 = fmaf(c1.x, wu1[4], a1);
                a0 = fmaf(c1.y, wu0[5], a0); a1 = fmaf(c1.y, wu1[5], a1);
                a0 = fmaf(c1.z, wu0[6], a0); a1 = fmaf(c1.z, wu1[6], a1);
                union { unsigned int u; bf16 h[2]; } pk;
                pk.h[0] = (bf16)ftanh(a0);
                pk.h[1] = (bf16)ftanh(a1);
                ((unsigned int*)xs)[node * (XSTR / 2) + cp] = pk.u;
            }
        }
        bf16x8 bfr[8];
        #pragma unroll
        for (int kk = 0; kk < 8; ++kk)
            bfr[kk] = *(const bf16x8*)(bq + p * 128 + kk * 16);
        __syncthreads();
        const bf16* xa = &xs[m * XSTR + q * 8];
        #pragma unroll
        for (int kk = 0; kk < 8; ++kk){
            bf16x8 a0 = *(const bf16x8*)(xa + kk * 16);
            bf16x8 a1 = *(const bf16x8*)(xa + kk * 16 + 32 * XSTR);
            acc0 = __builtin_amdgcn_mfma_f32_32x32x16_bf16(a0, bfr[kk], acc0, 0, 0, 0);
            acc1 = __builtin_amdgcn_mfma_f32_32x32x16_bf16(a1, bfr[kk], acc1, 0, 0, 0);
        }
    }
    const int colg = ct * 32 + m;
    const float bv = b_h[colg];
    #pragma unroll
    for (int nt = 0; nt < 2; ++nt){
        const floatx16* accp = nt ? &acc1 : &acc0;
        #pragma unroll
        for (int r = 0; r < 16; ++r){
            int row  = (r & 3) + 8 * (r >> 2) + 4 * q;
            int node = block0 + nt * 32 + row;
            out_b[(size_t)node * NH + colg] = (bf16)ftanh((*accp)[r] + bv);
        }
    }
}

// ---------- launch 4: k_tailA (r10-proven, unchanged) ----------
__global__ __launch_bounds__(256, 2) void k_tailA(
    const int* __restrict__ ids_A, const bf16* __restrict__ u_small,
    const bf16* __restrict__ wb, const float* __restrict__ b_h,
    const bf16* __restrict__ emb10, bf16* __restrict__ emb4)
{
    __shared__ bf16 xs[32 * XSTR3];
    __shared__ bf16 embL[32 * 136];
    __shared__ int ids[128];
    const int t = threadIdx.x, root = blockIdx.x;
    const int ct = t >> 6, lane = t & 63, m = lane & 31, q = lane >> 5;
    const float bv = b_h[ct * 32 + m];
    if (t < 32) ((uint4*)ids)[t] = ((const uint4*)(ids_A + root * 128))[t];
    __syncthreads();
    const bf16* bq = wb + ((size_t)(ct * 32 + m) * 384 + q * 8);

    #pragma unroll 1
    for (int l = 9; l >= 4; --l){
        const int n = 1 << (l - 4);
        #pragma unroll 1
        for (int r = 0; r < 4; ++r){
            int task = r * 256 + t;
            if (task < n * 32){
                int i = task >> 5, half = (task >> 4) & 1, part = task & 15;
                uint4 v;
                if (l == 9) v = *(const uint4*)(emb10 + (size_t)ids[63 + 2*i + half] * NH + part * 8);
                else        v = *(uint4*)&embL[(2*i + half) * 136 + part * 8];
                *(uint4*)&xs[i * XSTR3 + half * 128 + part * 8] = v;
            }
        }
        #pragma unroll 1
        for (int r = 0; r < 2; ++r){
            int task = r * 256 + t;
            if (task < n * 16){
                int i = task >> 4, part = task & 15;
                size_t row = (size_t)64 * ((1u << l) - 1) + ids[(n - 1) + i];
                *(uint4*)&xs[i * XSTR3 + 256 + part * 8] =
                    *(const uint4*)(u_small + row * NH + part * 8);
            }
        }
        __syncthreads();
        floatx16 accs[3];
        #pragma unroll
        for (int g = 0; g < 3; ++g) accs[g] = (floatx16){0,0,0,0,0,0,0,0,0,0,0,0,0,0,0,0};
        const bf16* xa = &xs[m * XSTR3 + q * 8];
        #pragma unroll
        for (int grp = 0; grp < 3; ++grp){
            bf16x8 bfr[8];
            #pragma unroll
            for (int kk = 0; kk < 8; ++kk)
                bfr[kk] = *(const bf16x8*)(bq + grp * 128 + kk * 16);
            #pragma unroll
            for (int kk = 0; kk < 8; ++kk){
                bf16x8 a0 = *(const bf16x8*)(xa + grp * 128 + kk * 16);
                accs[grp] = __builtin_amdgcn_mfma_f32_32x32x16_bf16(a0, bfr[kk], accs[grp], 0, 0, 0);
            }
        }
        floatx16 acc = accs[0] + accs[1] + accs[2];
        __syncthreads();
        #pragma unroll
        for (int r = 0; r < 16; ++r){
            int row = (r & 3) + 8 * (r >> 2) + 4 * q;
            if (row < n){
                float v = ftanh(acc[r] + bv);
                if (l > 4) embL[row * 136 + ct * 32 + m] = (bf16)v;
                else       emb4[(size_t)root * NH + ct * 32 + m] = (bf16)v;
            }
        }
        __syncthreads();
    }
}

// ---------- launch 5: k_tailB (r10-proven, unchanged) ----------
__global__ __launch_bounds__(256, 2) void k_tailB(
    const int* __restrict__ ids_B, const bf16* __restrict__ u_small,
    const bf16* __restrict__ wb, const float* __restrict__ b_h,
    const bf16* __restrict__ emb4, float* __restrict__ out_f)
{
    __shared__ bf16 xs[8 * XSTR3];
    __shared__ bf16 embL[8 * 136];
    __shared__ int ids[32];
    const int t = threadIdx.x, root = blockIdx.x;
    const int ct = t >> 6, lane = t & 63, m = lane & 31, q = lane >> 5;
    const float bv = b_h[ct * 32 + m];
    if (t < 8) ((uint4*)ids)[t] = ((const uint4*)(ids_B + root * 32))[t];
    __syncthreads();
    const bf16* bq = wb + ((size_t)(ct * 32 + m) * 384 + q * 8);

    #pragma unroll 1
    for (int l = 3; l >= 0; --l){
        const int n = 1 << l;
        {
            int task = t;
            if (task < n * 32){
                int i = task >> 5, half = (task >> 4) & 1, part = task & 15;
                uint4 v;
                if (l == 3) v = *(const uint4*)(emb4 + (size_t)ids[15 + 2*i + half] * NH + part * 8);
                else        v = *(uint4*)&embL[(2*i + half) * 136 + part * 8];
                *(uint4*)&xs[i * XSTR3 + half * 128 + part * 8] = v;
            }
            if (task < n * 16){
                int i = task >> 4, part = task & 15;
                size_t row = (size_t)64 * ((1u << l) - 1) + ids[(n - 1) + i];
                *(uint4*)&xs[i * XSTR3 + 256 + part * 8] =
                    *(const uint4*)(u_small + row * NH + part * 8);
            }
        }
        __syncthreads();
        floatx16 accs[3];
        #pragma unroll
        for (int g = 0; g < 3; ++g) accs[g] = (floatx16){0,0,0,0,0,0,0,0,0,0,0,0,0,0,0,0};
        const bf16* xa = &xs[m * XSTR3 + q * 8];
        #pragma unroll
        for (int grp = 0; grp < 3; ++grp){
            bf16x8 bfr[8];
            #pragma unroll
            for (int kk = 0; kk < 8; ++kk)
                bfr[kk] = *(const bf16x8*)(bq + grp * 128 + kk * 16);
            #pragma unroll
            for (int kk = 0; kk < 8; ++kk){
                bf16x8 a0 = *(const bf16x8*)(xa + grp * 128 + kk * 16);
                accs[grp] = __builtin_amdgcn_mfma_f32_32x32x16_bf16(a0, bfr[kk], accs[grp], 0, 0, 0);
            }
        }
        floatx16 acc = accs[0] + accs[1] + accs[2];
        __syncthreads();
        #pragma unroll
        for (int r = 0; r < 16; ++r){
            int row = (r & 3) + 8 * (r >> 2) + 4 * q;
            if (row < n){
                float v = ftanh(acc[r] + bv);
                if (l > 0) embL[row * 136 + ct * 32 + m] = (bf16)v;
                else       out_f[(size_t)root * NH + ct * 32 + m] = v;
            }
        }
        __syncthreads();
    }
}

// ---------- launcher ----------
extern "C" void kernel_launch(void* const* d_in, const int* in_sizes, int n_in,
                              void* d_out, int out_size, void* d_ws, size_t ws_size,
                              hipStream_t stream){
    const float* contents = (const float*)d_in[0];
    const int2*  children = (const int2*)d_in[1];
    const float* w_u      = (const float*)d_in[2];
    const float* b_u      = (const float*)d_in[3];
    const float* w_h      = (const float*)d_in[4];
    const float* b_h      = (const float*)d_in[5];
    float* outf = (float*)d_out;

    // ws: embA 16.8MB (emb10) | embB 33.6MB (emb11/emb4) | wb 96KB |
    //     u_small 16.8MB (levels 0..9) | ids_A 512KB | ids_B 8KB | w_ub 4KB
    bf16* embA    = (bf16*)d_ws;
    bf16* embB    = embA + (size_t)65536 * NH;
    bf16* wb      = embB + (size_t)131072 * NH;
    bf16* u_small = wb + (size_t)NH * 384;
    int*  ids_A   = (int*)(u_small + (size_t)65536 * NH);
    int*  ids_B   = ids_A + 1024 * 128;
    bf16* w_ub    = (bf16*)(ids_B + 64 * 32);

    hipLaunchKernelGGL(k_prep0, dim3(197), dim3(256), 0, stream,
                       children, w_u, b_u, w_h, ids_A, ids_B, wb, w_ub);
    hipLaunchKernelGGL(k_lvl11, dim3(2560), dim3(256), 0, stream,
                       contents, children, w_u, b_u, w_ub, wb, b_h,
                       embB, (unsigned int*)u_small);
    hipLaunchKernelGGL(k_inner, dim3(1024), dim3(256), 0, stream,
                       children + 65472, contents + (size_t)65472 * NF,
                       w_u, b_u, wb, b_h, embB, embA);
    hipLaunchKernelGGL(k_tailA, dim3(1024), dim3(256), 0, stream,
                       ids_A, u_small, wb, b_h, embA, embB);
    hipLaunchKernelGGL(k_tailB, dim3(64), dim3(256), 0, stream,
                       ids_B, u_small, wb, b_h, embB, outf);
}